// Round 2
// baseline (4913.646 us; speedup 1.0000x reference)
//
#include <hip/hip_runtime.h>

// ---------------- problem constants ----------------
#define SDIM 2
#define HDIM 1024
#define INPD 64
#define BB   128
#define SS   256
#define KORG 1090            // 2 x + 64 u + 1024 h
#define KP   1120            // padded: [u(0:64) | h(64:1088) | x(1088:1090) | 0(1090:1120)]
#define KT   35              // 1120/32 k-tiles
#define APITCH 1128          // LDS row pitch (elements) for bank spread

// output offsets (f32 elements)
#define OUT0 0               // outputs (B,S,1026)
#define OUT1 33619968        // z_f (1,B,1026)
#define OUT2 33751296        // c_z_f (1,B,1026)
#define OUT3 33882624        // coefficients (B,S,2)

typedef __attribute__((ext_vector_type(8))) _Float16 h8;
typedef __attribute__((ext_vector_type(4))) float f32x4;

__device__ inline unsigned short f2h(float f){
  union { _Float16 h; unsigned short u; } v;
  v.h = (_Float16)f;                       // RN conversion
  return v.u;
}
__device__ inline float sigm(float x){ return 1.0f / (1.0f + __expf(-x)); }
__device__ inline float tanh_(float x){
  x = fminf(20.f, fmaxf(-20.f, x));
  float e = __expf(2.0f * x);
  return (e - 1.0f) / (e + 1.0f);
}
// Builtin MFMA: compiler inserts all required hazard wait-states.
__device__ inline f32x4 MFMA(h8 a, h8 b, f32x4 c){
  return __builtin_amdgcn_mfma_f32_16x16x32_f16(a, b, c, 0, 0, 0);
}

// ---------------- prep kernels ----------------
// W' f16 [4096][KP], row r=4j+g <- orig row g*1024+j ; cols: k<1088 -> orig k+2,
// 1088/1089 -> orig 0/1 (x), else 0.  Also bias perm + W4' (Wa;Wx rows 0..3).
__global__ void prep_weights(const float* __restrict__ WU_w, const float* __restrict__ WU_b,
                             const float* __restrict__ Wa_w, const float* __restrict__ Wx_w,
                             unsigned short* __restrict__ Wp, float* __restrict__ Wbp,
                             unsigned short* __restrict__ W4p, unsigned* __restrict__ bar){
  int r = blockIdx.x;                 // 0..4095
  int g = r & 3, j = r >> 2;
  int ro = g * 1024 + j;
  for (int k = threadIdx.x; k < KP; k += 256){
    float v = 0.f;
    if (k < 1088)      v = WU_w[(size_t)ro * KORG + k + 2];
    else if (k < 1090) v = WU_w[(size_t)ro * KORG + (k - 1088)];
    Wp[(size_t)r * KP + k] = f2h(v);
  }
  if (threadIdx.x == 0) Wbp[r] = WU_b[ro];
  if (blockIdx.x == 0){
    for (int idx = threadIdx.x; idx < 16 * KP; idx += 256){
      int rr = idx / KP, k = idx % KP;
      float v = 0.f;
      if (rr < 4 && k >= 64 && k < 1088){
        int jj = k - 64;
        v = (rr < 2) ? Wa_w[rr * HDIM + jj] : Wx_w[(rr - 2) * HDIM + jj];
      }
      W4p[idx] = f2h(v);
    }
    if (threadIdx.x < 8) bar[threadIdx.x * 64] = 0u;
  }
}

__global__ void prep_ubuf(const float* __restrict__ rnn, unsigned short* __restrict__ ubuf){
  int idx = blockIdx.x * 256 + threadIdx.x;     // over S*B*64
  if (idx >= SS * BB * INPD) return;
  int i = idx & 63, b = (idx >> 6) & 127, t = idx >> 13;
  ubuf[idx] = f2h(rnn[((size_t)b * SS + t) * INPD + i]);
}

__global__ void prep_h0(const float* __restrict__ z0, unsigned short* __restrict__ hbuf){
  int idx = blockIdx.x * 256 + threadIdx.x;     // over B*H
  if (idx >= BB * HDIM) return;
  int j = idx & 1023, m = idx >> 10;
  hbuf[idx] = f2h(z0[m * 1026 + 2 + j]);
}

// ---------------- persistent scan kernel ----------------
// grid 256 = 8 m-chunks x 32 n-chunks; 4 waves; weights persistent in VGPRs.
__global__ __launch_bounds__(256, 1) void lstm_persist(
    const unsigned short* __restrict__ Wp, const float* __restrict__ Wbp,
    const unsigned short* __restrict__ W4p, const unsigned short* __restrict__ ubuf,
    unsigned short* __restrict__ hbuf, unsigned* __restrict__ bar,
    const float* __restrict__ z0, const float* __restrict__ c0,
    const float* __restrict__ tau, const float* __restrict__ Amat,
    const float* __restrict__ Wab, const float* __restrict__ Wxb,
    float* __restrict__ out)
{
  const int tid = threadIdx.x;
  const int bid = blockIdx.x;
  const int mc = bid & 7, nc = bid >> 3;
  const int wid = tid >> 6, lane = tid & 63;
  const int q = lane >> 4, s = lane & 15;

  __shared__ __align__(16) unsigned short acts[16][APITCH];
  __shared__ float scratch[4][16][4];
  __shared__ float xst[16][2];

  // zero pad cols 1090..APITCH once; init x state from z0
  for (int z = tid; z < 16 * (APITCH - 1090); z += 256){
    int m = z / (APITCH - 1090), k = 1090 + z % (APITCH - 1090);
    acts[m][k] = 0;
  }
  if (tid < 16){
    xst[tid][0] = z0[(mc * 16 + tid) * 1026 + 0];
    xst[tid][1] = z0[(mc * 16 + tid) * 1026 + 1];
  }

  // persistent weight fragments: wave owns 32 gate-rows (2 n-tiles) x all K
  h8 W[2][KT];
  {
    const unsigned short* wb = Wp + (size_t)(nc * 128 + wid * 32) * KP;
    #pragma unroll
    for (int nt = 0; nt < 2; ++nt)
      #pragma unroll
      for (int kt = 0; kt < KT; ++kt)
        W[nt][kt] = *(const h8*)&wb[(nt * 16 + s) * KP + kt * 32 + q * 8];
  }
  h8 W4[8];                       // alpha/x_tilde frags, wave covers kt 2+8w..+8
  #pragma unroll
  for (int i = 0; i < 8; ++i){
    int kt = 2 + wid * 8 + i;
    W4[i] = *(const h8*)&W4p[s * KP + kt * 32 + q * 8];
  }
  float bias0[4], bias1[4];
  #pragma unroll
  for (int r = 0; r < 4; ++r){
    bias0[r] = Wbp[nc * 128 + wid * 32 + 0  + q * 4 + r];
    bias1[r] = Wbp[nc * 128 + wid * 32 + 16 + q * 4 + r];
  }
  float cst[2];                    // persistent c state (one hidden unit per (lane,nt))
  #pragma unroll
  for (int nt = 0; nt < 2; ++nt){
    int j = nc * 32 + wid * 8 + nt * 4 + q;
    cst[nt] = c0[(mc * 16 + s) * 1026 + 2 + j];
  }

  const int m_l = tid & 15, seg = tid >> 4;     // staging map (LDS bank-friendly)
  const int mg = mc * 16 + m_l;

  for (int it = 0; it <= SS; ++it){
    const int p = it & 1;
    // ---- stage h (and u) into LDS ----
    {
      const unsigned short* hs = hbuf + p * (BB * HDIM) + mg * HDIM + seg * 64;
      #pragma unroll
      for (int e = 0; e < 8; ++e)
        *(h8*)&acts[m_l][64 + seg * 64 + e * 8] = *(const h8*)&hs[e * 8];
      if (it < SS && seg < 8){
        const unsigned short* us = ubuf + (size_t)it * (BB * INPD) + mg * INPD + seg * 8;
        *(h8*)&acts[m_l][seg * 8] = *(const h8*)us;
      }
    }
    __syncthreads();
    // ---- alpha(t-1) / x(t-1) from staged h ----
    if (it > 0){
      f32x4 pacc = {0.f, 0.f, 0.f, 0.f};
      #pragma unroll
      for (int i = 0; i < 8; ++i){
        int kt = 2 + wid * 8 + i;
        h8 b = *(const h8*)&acts[s][kt * 32 + q * 8];
        pacc = MFMA(W4[i], b, pacc);
      }
      if (q == 0){
        #pragma unroll
        for (int r = 0; r < 4; ++r) scratch[wid][s][r] = pacc[r];
      }
      __syncthreads();
      if (tid < 16){
        float d0 = 0, d1 = 0, d2 = 0, d3 = 0;
        #pragma unroll
        for (int w = 0; w < 4; ++w){
          d0 += scratch[w][tid][0]; d1 += scratch[w][tid][1];
          d2 += scratch[w][tid][2]; d3 += scratch[w][tid][3];
        }
        int t = it - 1;
        int m = mc * 16 + tid;
        float a0 = sigm(d0 + Wab[0]), a1 = sigm(d1 + Wab[1]);
        float xt0 = d2 + Wxb[0], xt1 = d3 + Wxb[1];
        float x0 = xst[tid][0], x1 = xst[tid][1];
        float ta = tau[m * SS + t];
        float xm0 = x0 + ta * (Amat[0] * x0 + Amat[1] * x1);
        float xm1 = x1 + ta * (Amat[2] * x0 + Amat[3] * x1);
        float xn0 = a0 * xm0 + (1.f - a0) * xt0;
        float xn1 = a1 * xm1 + (1.f - a1) * xt1;
        xst[tid][0] = xn0; xst[tid][1] = xn1;
        acts[tid][1088] = f2h(xn0); acts[tid][1089] = f2h(xn1);
        if (nc == 0){
          out[(size_t)m * 262656 + t * 1026 + 0] = xn0;
          out[(size_t)m * 262656 + t * 1026 + 1] = xn1;
          out[OUT3 + m * 512 + t * 2 + 0] = a0;
          out[OUT3 + m * 512 + t * 2 + 1] = a1;
          if (t == SS - 1){
            out[OUT1 + m * 1026 + 0] = xn0;
            out[OUT1 + m * 1026 + 1] = xn1;
            out[OUT2 + m * 1026 + 0] = c0[m * 1026 + 0];   // c_x never changes
            out[OUT2 + m * 1026 + 1] = c0[m * 1026 + 1];
          }
        }
      }
    } else {
      if (tid < 16){
        acts[tid][1088] = f2h(xst[tid][0]);
        acts[tid][1089] = f2h(xst[tid][1]);
      }
    }
    __syncthreads();
    // ---- GEMM + LSTM elementwise ----
    if (it < SS){
      f32x4 acc0 = {bias0[0], bias0[1], bias0[2], bias0[3]};
      f32x4 acc1 = {bias1[0], bias1[1], bias1[2], bias1[3]};
      #pragma unroll
      for (int kt = 0; kt < KT; ++kt){
        h8 b = *(const h8*)&acts[s][kt * 32 + q * 8];
        acc0 = MFMA(W[0][kt], b, acc0);
        acc1 = MFMA(W[1][kt], b, acc1);
      }
      int m = mc * 16 + s;
      unsigned short* hw = hbuf + (p ^ 1) * (BB * HDIM) + m * HDIM;
      #pragma unroll
      for (int nt = 0; nt < 2; ++nt){
        f32x4 a = nt ? acc1 : acc0;       // a[0]=i, a[1]=f, a[2]=g, a[3]=o
        float cn = sigm(a[1]) * cst[nt] + sigm(a[0]) * tanh_(a[2]);
        float hn = sigm(a[3]) * tanh_(cn);
        cst[nt] = cn;
        int j = nc * 32 + wid * 8 + nt * 4 + q;
        hw[j] = f2h(hn);
        out[(size_t)m * 262656 + it * 1026 + 2 + j] = hn;
        if (it == SS - 1){
          out[OUT1 + m * 1026 + 2 + j] = hn;
          out[OUT2 + m * 1026 + 2 + j] = cn;
        }
      }
      // ---- mc-group barrier (32 blocks), grid.sync pattern ----
      __syncthreads();
      if (tid == 0){
        __threadfence();
        atomicAdd(&bar[mc * 64], 1u);
        unsigned tgt = 32u * (unsigned)(it + 1);
        while (__hip_atomic_load(&bar[mc * 64], __ATOMIC_RELAXED, __HIP_MEMORY_SCOPE_AGENT) < tgt)
          __builtin_amdgcn_s_sleep(2);
        __threadfence();
      }
      __syncthreads();
    }
  }
}

// ---------------- launch ----------------
extern "C" void kernel_launch(void* const* d_in, const int* in_sizes, int n_in,
                              void* d_out, int out_size, void* d_ws, size_t ws_size,
                              hipStream_t stream) {
  const float* rnn  = (const float*)d_in[0];
  const float* z0   = (const float*)d_in[1];
  const float* c0   = (const float*)d_in[2];
  const float* tau  = (const float*)d_in[3];
  const float* Amat = (const float*)d_in[4];
  const float* WU_w = (const float*)d_in[5];
  const float* WU_b = (const float*)d_in[6];
  const float* Wa_w = (const float*)d_in[7];
  const float* Wa_b = (const float*)d_in[8];
  const float* Wx_w = (const float*)d_in[9];
  const float* Wx_b = (const float*)d_in[10];

  char* ws = (char*)d_ws;
  unsigned short* Wp   = (unsigned short*)(ws + 0);          // 4096*1120*2 = 9,175,040
  float*          Wbp  = (float*)(ws + 9175040);             // 16,384
  unsigned short* W4p  = (unsigned short*)(ws + 9191424);    // 16*1120*2 = 35,840
  unsigned short* ubuf = (unsigned short*)(ws + 9227264);    // 256*128*64*2 = 4,194,304
  unsigned short* hbuf = (unsigned short*)(ws + 13421568);   // 2*128*1024*2 = 524,288
  unsigned*       bar  = (unsigned*)(ws + 13945856);         // 8 counters, 256B apart

  prep_weights<<<4096, 256, 0, stream>>>(WU_w, WU_b, Wa_w, Wx_w, Wp, Wbp, W4p, bar);
  prep_ubuf<<<8192, 256, 0, stream>>>(rnn, ubuf);
  prep_h0<<<512, 256, 0, stream>>>(z0, hbuf);
  lstm_persist<<<256, 256, 0, stream>>>(Wp, Wbp, W4p, ubuf, hbuf, bar,
                                        z0, c0, tau, Amat, Wa_b, Wx_b, (float*)d_out);
}

// Round 6
// 1999.467 us; speedup vs baseline: 2.4575x; 2.4575x over previous
//
#include <hip/hip_runtime.h>

// ---------------- problem constants ----------------
#define SDIM 2
#define HDIM 1024
#define INPD 64
#define BB   128
#define SS   256
#define KORG 1090            // 2 x + 64 u + 1024 h
#define KP   1120            // padded: [u(0:64) | h(64:1088) | x(1088:1090) | 0(1090:1120)]
#define KT   35              // 1120/32 k-tiles
#define APITCH 1128          // LDS row pitch (elements) for bank spread

// output offsets (f32 elements)
#define OUT0 0               // outputs (B,S,1026)
#define OUT1 33619968        // z_f (1,B,1026)
#define OUT2 33751296        // c_z_f (1,B,1026)
#define OUT3 33882624        // coefficients (B,S,2)

typedef __attribute__((ext_vector_type(8))) _Float16 h8;
typedef __attribute__((ext_vector_type(4))) float f32x4;

__device__ inline unsigned short f2h(float f){
  union { _Float16 h; unsigned short u; } v;
  v.h = (_Float16)f;
  return v.u;
}
__device__ inline float sigm(float x){ return 1.0f / (1.0f + __expf(-x)); }
__device__ inline float tanh_(float x){
  x = fminf(20.f, fmaxf(-20.f, x));
  float e = __expf(2.0f * x);
  return (e - 1.0f) / (e + 1.0f);
}
__device__ inline f32x4 MFMA(h8 a, h8 b, f32x4 c){
  return __builtin_amdgcn_mfma_f32_16x16x32_f16(a, b, c, 0, 0, 0);
}

// hbuf column permutation: within each aligned 8-block of h indices,
// hbuf position p holds original h index g(p) = (p&1)*4 + (p>>1).
// (writer thread (nt,q) stores its pair {nt=0,nt=1} packed at pos q*2.)
__device__ __host__ inline int origH(int jpos){
  int pos = jpos & 7;
  return (jpos & ~7) + ((pos & 1) * 4) + (pos >> 1);
}

// ---------------- prep kernels ----------------
__global__ void prep_weights(const float* __restrict__ WU_w, const float* __restrict__ WU_b,
                             const float* __restrict__ Wa_w, const float* __restrict__ Wx_w,
                             unsigned short* __restrict__ Wp, float* __restrict__ Wbp,
                             unsigned short* __restrict__ W4p, unsigned* __restrict__ bar){
  int r = blockIdx.x;                 // 0..4095
  int g = r & 3, j = r >> 2;
  int ro = g * 1024 + j;
  for (int k = threadIdx.x; k < KP; k += 256){
    float v = 0.f;
    if (k < 64)        v = WU_w[(size_t)ro * KORG + k + 2];
    else if (k < 1088) v = WU_w[(size_t)ro * KORG + 66 + origH(k - 64)];
    else if (k < 1090) v = WU_w[(size_t)ro * KORG + (k - 1088)];
    Wp[(size_t)r * KP + k] = f2h(v);
  }
  if (threadIdx.x == 0) Wbp[r] = WU_b[ro];
  if (blockIdx.x == 0){
    for (int idx = threadIdx.x; idx < 16 * KP; idx += 256){
      int rr = idx / KP, k = idx % KP;
      float v = 0.f;
      if (rr < 4 && k >= 64 && k < 1088){
        int jj = origH(k - 64);
        v = (rr < 2) ? Wa_w[rr * HDIM + jj] : Wx_w[(rr - 2) * HDIM + jj];
      }
      W4p[idx] = f2h(v);
    }
    bar[threadIdx.x] = 0u;            // 256 flags (8 groups x 32 blocks)
  }
}

__global__ void prep_ubuf(const float* __restrict__ rnn, unsigned short* __restrict__ ubuf){
  int idx = blockIdx.x * 256 + threadIdx.x;     // over S*B*64
  if (idx >= SS * BB * INPD) return;
  int i = idx & 63, b = (idx >> 6) & 127, t = idx >> 13;
  ubuf[idx] = f2h(rnn[((size_t)b * SS + t) * INPD + i]);
}

__global__ void prep_h0(const float* __restrict__ z0, unsigned short* __restrict__ hbuf){
  int idx = blockIdx.x * 256 + threadIdx.x;     // over B*H
  if (idx >= BB * HDIM) return;
  int jp = idx & 1023, m = idx >> 10;
  hbuf[idx] = f2h(z0[m * 1026 + 2 + origH(jp)]);
}

// ---------------- persistent scan kernel ----------------
// grid 256 = 8 m-chunks x 32 n-chunks; 4 waves; weights persistent in regs.
// Sync: per-block flags + write-through (sc0 sc1) h exchange via MALL.
// No __threadfence (avoids buffer_wbl2 L2 writebacks), no atomics.
__global__ __launch_bounds__(256, 1) void lstm_persist(
    const unsigned short* __restrict__ Wp, const float* __restrict__ Wbp,
    const unsigned short* __restrict__ W4p, const unsigned short* __restrict__ ubuf,
    unsigned short* __restrict__ hbuf, unsigned* __restrict__ bar,
    const float* __restrict__ z0, const float* __restrict__ c0,
    const float* __restrict__ tau, const float* __restrict__ Amat,
    const float* __restrict__ Wab, const float* __restrict__ Wxb,
    float* __restrict__ out)
{
  const int tid = threadIdx.x;
  const int bid = blockIdx.x;
  const int mc = bid & 7, nc = bid >> 3;
  const int wid = tid >> 6, lane = tid & 63;
  const int q = lane >> 4, s = lane & 15;

  __shared__ __align__(16) unsigned short acts[16][APITCH];
  __shared__ float scratch[4][16][4];
  __shared__ float xst[16][2];

  for (int z = tid; z < 16 * (APITCH - 1090); z += 256){
    int m = z / (APITCH - 1090), k = 1090 + z % (APITCH - 1090);
    acts[m][k] = 0;
  }
  if (tid < 16){
    xst[tid][0] = z0[(mc * 16 + tid) * 1026 + 0];
    xst[tid][1] = z0[(mc * 16 + tid) * 1026 + 1];
  }

  // persistent weight fragments: wave owns 32 gate-rows (2 n-tiles) x all K
  h8 W[2][KT];
  {
    const unsigned short* wb = Wp + (size_t)(nc * 128 + wid * 32) * KP;
    #pragma unroll
    for (int nt = 0; nt < 2; ++nt)
      #pragma unroll
      for (int kt = 0; kt < KT; ++kt)
        W[nt][kt] = *(const h8*)&wb[(nt * 16 + s) * KP + kt * 32 + q * 8];
  }
  h8 W4[8];
  #pragma unroll
  for (int i = 0; i < 8; ++i){
    int kt = 2 + wid * 8 + i;
    W4[i] = *(const h8*)&W4p[s * KP + kt * 32 + q * 8];
  }
  float bias0[4], bias1[4];
  #pragma unroll
  for (int r = 0; r < 4; ++r){
    bias0[r] = Wbp[nc * 128 + wid * 32 + 0  + q * 4 + r];
    bias1[r] = Wbp[nc * 128 + wid * 32 + 16 + q * 4 + r];
  }
  float cst[2];
  #pragma unroll
  for (int nt = 0; nt < 2; ++nt){
    int j = nc * 32 + wid * 8 + nt * 4 + q;
    cst[nt] = c0[(mc * 16 + s) * 1026 + 2 + j];
  }

  const int m_l = tid & 15, seg = tid >> 4;
  const int mg = mc * 16 + m_l;

  for (int it = 0; it <= SS; ++it){
    const int p = it & 1;
    // ---- stage h (agent-coherent loads; T14: issue, waitcnt, then LDS) ----
    {
      const unsigned short* hs = hbuf + p * (BB * HDIM) + mg * HDIM + seg * 64;
      h8 t0, t1, t2, t3, t4, t5, t6, t7;
      asm volatile("global_load_dwordx4 %0, %1, off sc0 sc1"            : "=&v"(t0) : "v"(hs) : "memory");
      asm volatile("global_load_dwordx4 %0, %1, off offset:16 sc0 sc1"  : "=&v"(t1) : "v"(hs) : "memory");
      asm volatile("global_load_dwordx4 %0, %1, off offset:32 sc0 sc1"  : "=&v"(t2) : "v"(hs) : "memory");
      asm volatile("global_load_dwordx4 %0, %1, off offset:48 sc0 sc1"  : "=&v"(t3) : "v"(hs) : "memory");
      asm volatile("global_load_dwordx4 %0, %1, off offset:64 sc0 sc1"  : "=&v"(t4) : "v"(hs) : "memory");
      asm volatile("global_load_dwordx4 %0, %1, off offset:80 sc0 sc1"  : "=&v"(t5) : "v"(hs) : "memory");
      asm volatile("global_load_dwordx4 %0, %1, off offset:96 sc0 sc1"  : "=&v"(t6) : "v"(hs) : "memory");
      asm volatile("global_load_dwordx4 %0, %1, off offset:112 sc0 sc1" : "=&v"(t7) : "v"(hs) : "memory");
      h8 uvec = {};
      bool do_u = (it < SS) && (seg < 8);
      if (do_u)
        uvec = *(const h8*)&ubuf[(size_t)it * (BB * INPD) + mg * INPD + seg * 8];
      asm volatile("s_waitcnt vmcnt(0)" ::: "memory");
      __builtin_amdgcn_sched_barrier(0);
      *(h8*)&acts[m_l][64 + seg * 64 +  0] = t0;
      *(h8*)&acts[m_l][64 + seg * 64 +  8] = t1;
      *(h8*)&acts[m_l][64 + seg * 64 + 16] = t2;
      *(h8*)&acts[m_l][64 + seg * 64 + 24] = t3;
      *(h8*)&acts[m_l][64 + seg * 64 + 32] = t4;
      *(h8*)&acts[m_l][64 + seg * 64 + 40] = t5;
      *(h8*)&acts[m_l][64 + seg * 64 + 48] = t6;
      *(h8*)&acts[m_l][64 + seg * 64 + 56] = t7;
      if (do_u) *(h8*)&acts[m_l][seg * 8] = uvec;
    }
    __syncthreads();
    // ---- alpha(t-1) / x(t-1) from staged h ----
    if (it > 0){
      f32x4 pacc = {0.f, 0.f, 0.f, 0.f};
      #pragma unroll
      for (int i = 0; i < 8; ++i){
        int kt = 2 + wid * 8 + i;
        h8 b = *(const h8*)&acts[s][kt * 32 + q * 8];
        pacc = MFMA(W4[i], b, pacc);
      }
      if (q == 0){
        #pragma unroll
        for (int r = 0; r < 4; ++r) scratch[wid][s][r] = pacc[r];
      }
      __syncthreads();
      if (tid < 16){
        float d0 = 0, d1 = 0, d2 = 0, d3 = 0;
        #pragma unroll
        for (int w = 0; w < 4; ++w){
          d0 += scratch[w][tid][0]; d1 += scratch[w][tid][1];
          d2 += scratch[w][tid][2]; d3 += scratch[w][tid][3];
        }
        int t = it - 1;
        int m = mc * 16 + tid;
        float a0 = sigm(d0 + Wab[0]), a1 = sigm(d1 + Wab[1]);
        float xt0 = d2 + Wxb[0], xt1 = d3 + Wxb[1];
        float x0 = xst[tid][0], x1 = xst[tid][1];
        float ta = tau[m * SS + t];
        float xm0 = x0 + ta * (Amat[0] * x0 + Amat[1] * x1);
        float xm1 = x1 + ta * (Amat[2] * x0 + Amat[3] * x1);
        float xn0 = a0 * xm0 + (1.f - a0) * xt0;
        float xn1 = a1 * xm1 + (1.f - a1) * xt1;
        xst[tid][0] = xn0; xst[tid][1] = xn1;
        acts[tid][1088] = f2h(xn0); acts[tid][1089] = f2h(xn1);
        if (nc == 0){
          out[(size_t)m * 262656 + t * 1026 + 0] = xn0;
          out[(size_t)m * 262656 + t * 1026 + 1] = xn1;
          out[OUT3 + m * 512 + t * 2 + 0] = a0;
          out[OUT3 + m * 512 + t * 2 + 1] = a1;
          if (t == SS - 1){
            out[OUT1 + m * 1026 + 0] = xn0;
            out[OUT1 + m * 1026 + 1] = xn1;
            out[OUT2 + m * 1026 + 0] = c0[m * 1026 + 0];
            out[OUT2 + m * 1026 + 1] = c0[m * 1026 + 1];
          }
        }
      }
    } else {
      if (tid < 16){
        acts[tid][1088] = f2h(xst[tid][0]);
        acts[tid][1089] = f2h(xst[tid][1]);
      }
    }
    __syncthreads();
    // ---- GEMM + LSTM elementwise + publish + flag barrier ----
    if (it < SS){
      f32x4 acc0 = {bias0[0], bias0[1], bias0[2], bias0[3]};
      f32x4 acc1 = {bias1[0], bias1[1], bias1[2], bias1[3]};
      #pragma unroll
      for (int kt = 0; kt < KT; ++kt){
        h8 b = *(const h8*)&acts[s][kt * 32 + q * 8];
        acc0 = MFMA(W[0][kt], b, acc0);
        acc1 = MFMA(W[1][kt], b, acc1);
      }
      int m = mc * 16 + s;
      float hnv[2];
      #pragma unroll
      for (int nt = 0; nt < 2; ++nt){
        f32x4 a = nt ? acc1 : acc0;       // a[0]=i, a[1]=f, a[2]=g, a[3]=o
        float cn = sigm(a[1]) * cst[nt] + sigm(a[0]) * tanh_(a[2]);
        float hn = sigm(a[3]) * tanh_(cn);
        cst[nt] = cn; hnv[nt] = hn;
        int j = nc * 32 + wid * 8 + nt * 4 + q;
        out[(size_t)m * 262656 + it * 1026 + 2 + j] = hn;
        if (it == SS - 1){
          out[OUT1 + m * 1026 + 2 + j] = hn;
          out[OUT2 + m * 1026 + 2 + j] = cn;
        }
      }
      // write-through publish (packed pair at permuted position q*2)
      {
        unsigned hv = (unsigned)f2h(hnv[0]) | ((unsigned)f2h(hnv[1]) << 16);
        unsigned short* hw = hbuf + (p ^ 1) * (BB * HDIM) + m * HDIM + nc * 32 + wid * 8 + q * 2;
        asm volatile("global_store_dword %0, %1, off sc0 sc1" :: "v"(hw), "v"(hv) : "memory");
      }
      asm volatile("s_waitcnt vmcnt(0)" ::: "memory");
      __syncthreads();
      if (tid == 0){
        unsigned* fl = bar + mc * 32 + nc;
        unsigned fv = (unsigned)(it + 1);
        asm volatile("global_store_dword %0, %1, off sc0 sc1" :: "v"(fl), "v"(fv) : "memory");
      }
      if (wid == 0){
        const unsigned* fp = bar + mc * 32 + (lane & 31);
        unsigned tgt = (unsigned)(it + 1);
        unsigned v;
        // bounded spin: never triggers when protocol is healthy; converts a
        // hypothetical deadlock into a wrong-answer (diagnosable) instead of
        // a container timeout.
        for (int spin = 0; spin < (1 << 20); ++spin){
          asm volatile("global_load_dword %0, %1, off sc0 sc1\n\ts_waitcnt vmcnt(0)"
                       : "=v"(v) : "v"(fp) : "memory");
          if (!__any((int)(v < tgt))) break;
        }
      }
      __syncthreads();
    }
  }
}

// ---------------- launch ----------------
extern "C" void kernel_launch(void* const* d_in, const int* in_sizes, int n_in,
                              void* d_out, int out_size, void* d_ws, size_t ws_size,
                              hipStream_t stream) {
  const float* rnn  = (const float*)d_in[0];
  const float* z0   = (const float*)d_in[1];
  const float* c0   = (const float*)d_in[2];
  const float* tau  = (const float*)d_in[3];
  const float* Amat = (const float*)d_in[4];
  const float* WU_w = (const float*)d_in[5];
  const float* WU_b = (const float*)d_in[6];
  const float* Wa_w = (const float*)d_in[7];
  const float* Wa_b = (const float*)d_in[8];
  const float* Wx_w = (const float*)d_in[9];
  const float* Wx_b = (const float*)d_in[10];

  char* ws = (char*)d_ws;
  unsigned short* Wp   = (unsigned short*)(ws + 0);          // 4096*1120*2 = 9,175,040
  float*          Wbp  = (float*)(ws + 9175040);             // 16,384
  unsigned short* W4p  = (unsigned short*)(ws + 9191424);    // 16*1120*2 = 35,840
  unsigned short* ubuf = (unsigned short*)(ws + 9227264);    // 256*128*64*2 = 4,194,304
  unsigned short* hbuf = (unsigned short*)(ws + 13421568);   // 2*128*1024*2 = 524,288
  unsigned*       bar  = (unsigned*)(ws + 13945856);         // 256 flags (8x32)

  prep_weights<<<4096, 256, 0, stream>>>(WU_w, WU_b, Wa_w, Wx_w, Wp, Wbp, W4p, bar);
  prep_ubuf<<<8192, 256, 0, stream>>>(rnn, ubuf);
  prep_h0<<<512, 256, 0, stream>>>(z0, hbuf);
  lstm_persist<<<256, 256, 0, stream>>>(Wp, Wbp, W4p, ubuf, hbuf, bar,
                                        z0, c0, tau, Amat, Wa_b, Wx_b, (float*)d_out);
}

// Round 7
// 1347.034 us; speedup vs baseline: 3.6478x; 1.4843x over previous
//
#include <hip/hip_runtime.h>

// ---------------- problem constants ----------------
#define SDIM 2
#define HDIM 1024
#define INPD 64
#define BB   128
#define SS   256
#define KORG 1090            // 2 x + 64 u + 1024 h
#define KP   1120            // Wp pitch: [u(0:64) | h(64:1088) | x(1088:1090) | 0]
#define KTM  34              // main GEMM k-tiles (u+h = 1088 cols)
#define APITCH 1096          // LDS row pitch (elements); 16B-quad stride 137 (odd) -> bank-uniform

// output offsets (f32 elements)
#define OUT0 0               // outputs (B,S,1026)
#define OUT1 33619968        // z_f (1,B,1026)
#define OUT2 33751296        // c_z_f (1,B,1026)
#define OUT3 33882624        // coefficients (B,S,2)

typedef __attribute__((ext_vector_type(8))) _Float16 h8;
typedef __attribute__((ext_vector_type(4))) float f32x4;

__device__ inline unsigned short f2h(float f){
  union { _Float16 h; unsigned short u; } v;
  v.h = (_Float16)f;
  return v.u;
}
__device__ inline float sigm(float x){ return 1.0f / (1.0f + __expf(-x)); }
__device__ inline float tanh_(float x){
  x = fminf(20.f, fmaxf(-20.f, x));
  float e = __expf(2.0f * x);
  return (e - 1.0f) / (e + 1.0f);
}
__device__ inline f32x4 MFMA(h8 a, h8 b, f32x4 c){
  return __builtin_amdgcn_mfma_f32_16x16x32_f16(a, b, c, 0, 0, 0);
}

// hbuf column permutation: within each aligned 8-block of h indices,
// hbuf position p holds original h index g(p) = (p&1)*4 + (p>>1).
__device__ __host__ inline int origH(int jpos){
  int pos = jpos & 7;
  return (jpos & ~7) + ((pos & 1) * 4) + (pos >> 1);
}

// ---------------- prep kernels ----------------
__global__ void prep_weights(const float* __restrict__ WU_w, const float* __restrict__ WU_b,
                             const float* __restrict__ Wa_w, const float* __restrict__ Wx_w,
                             unsigned short* __restrict__ Wp, float* __restrict__ Wbp,
                             unsigned short* __restrict__ W4p, unsigned* __restrict__ bar){
  int r = blockIdx.x;                 // 0..4095
  int g = r & 3, j = r >> 2;
  int ro = g * 1024 + j;
  for (int k = threadIdx.x; k < KP; k += 256){
    float v = 0.f;
    if (k < 64)        v = WU_w[(size_t)ro * KORG + k + 2];
    else if (k < 1088) v = WU_w[(size_t)ro * KORG + 66 + origH(k - 64)];
    else if (k < 1090) v = WU_w[(size_t)ro * KORG + (k - 1088)];
    Wp[(size_t)r * KP + k] = f2h(v);
  }
  if (threadIdx.x == 0) Wbp[r] = WU_b[ro];
  if (blockIdx.x == 0){
    for (int idx = threadIdx.x; idx < 16 * KP; idx += 256){
      int rr = idx / KP, k = idx % KP;
      float v = 0.f;
      if (rr < 4 && k >= 64 && k < 1088){
        int jj = origH(k - 64);
        v = (rr < 2) ? Wa_w[rr * HDIM + jj] : Wx_w[(rr - 2) * HDIM + jj];
      }
      W4p[idx] = f2h(v);
    }
    bar[threadIdx.x] = 0u;            // 256 flags (8 groups x 32 blocks)
  }
}

__global__ void prep_ubuf(const float* __restrict__ rnn, unsigned short* __restrict__ ubuf){
  int idx = blockIdx.x * 256 + threadIdx.x;     // over S*B*64
  if (idx >= SS * BB * INPD) return;
  int i = idx & 63, b = (idx >> 6) & 127, t = idx >> 13;
  ubuf[idx] = f2h(rnn[((size_t)b * SS + t) * INPD + i]);
}

__global__ void prep_h0(const float* __restrict__ z0, unsigned short* __restrict__ hbuf){
  int idx = blockIdx.x * 256 + threadIdx.x;     // over B*H
  if (idx >= BB * HDIM) return;
  int jp = idx & 1023, m = idx >> 10;
  hbuf[idx] = f2h(z0[m * 1026 + 2 + origH(jp)]);
}

// ---------------- persistent scan kernel ----------------
// grid 256 = 8 m-chunks x 32 n-chunks; 4 waves; weights persistent in regs.
// Sync: per-block flags + write-through (sc0 sc1) h exchange via MALL.
__global__ __launch_bounds__(256, 1) void lstm_persist(
    const unsigned short* __restrict__ Wp, const float* __restrict__ Wbp,
    const unsigned short* __restrict__ W4p, const unsigned short* __restrict__ ubuf,
    unsigned short* __restrict__ hbuf, unsigned* __restrict__ bar,
    const float* __restrict__ z0, const float* __restrict__ c0,
    const float* __restrict__ tau, const float* __restrict__ Amat,
    const float* __restrict__ Wab, const float* __restrict__ Wxb,
    float* __restrict__ out)
{
  const int tid = threadIdx.x;
  const int bid = blockIdx.x;
  const int mc = bid & 7, nc = bid >> 3;
  const int wid = tid >> 6, lane = tid & 63;
  const int q = lane >> 4, s = lane & 15;

  __shared__ __align__(16) unsigned short acts[16][APITCH];
  __shared__ float tau_lds[16][SS];
  __shared__ float scratch[4][16][4];
  __shared__ float xst[16][2];

  if (tid < 16){
    xst[tid][0] = z0[(mc * 16 + tid) * 1026 + 0];
    xst[tid][1] = z0[(mc * 16 + tid) * 1026 + 1];
  }
  // tau -> LDS (coalesced, once)
  {
    int r = tid >> 4, c = tid & 15;
    for (int i = 0; i < 16; ++i)
      tau_lds[r][c + 16 * i] = tau[(mc * 16 + r) * SS + c + 16 * i];
  }
  // small constants -> regs (off the serial path)
  const float A00 = Amat[0], A01 = Amat[1], A10 = Amat[2], A11 = Amat[3];
  const float wab0 = Wab[0], wab1 = Wab[1];
  const float wxb0 = Wxb[0], wxb1 = Wxb[1];

  // persistent weight fragments: wave owns 32 gate-rows (2 n-tiles) x K=1088
  h8 W[2][KTM];
  {
    const unsigned short* wb = Wp + (size_t)(nc * 128 + wid * 32) * KP;
    #pragma unroll
    for (int nt = 0; nt < 2; ++nt)
      #pragma unroll
      for (int kt = 0; kt < KTM; ++kt)
        W[nt][kt] = *(const h8*)&wb[(nt * 16 + s) * KP + kt * 32 + q * 8];
  }
  h8 W4[8];
  #pragma unroll
  for (int i = 0; i < 8; ++i){
    int kt = 2 + wid * 8 + i;
    W4[i] = *(const h8*)&W4p[s * KP + kt * 32 + q * 8];
  }
  // x-column weights (rank-2 update), f32
  float wxa_[2][4], wxb_[2][4];
  #pragma unroll
  for (int nt = 0; nt < 2; ++nt)
    #pragma unroll
    for (int r = 0; r < 4; ++r){
      size_t rg = (size_t)(nc * 128 + wid * 32 + nt * 16 + q * 4 + r) * KP;
      wxa_[nt][r] = (float)(*(const _Float16*)&Wp[rg + 1088]);
      wxb_[nt][r] = (float)(*(const _Float16*)&Wp[rg + 1089]);
    }
  float bias0[4], bias1[4];
  #pragma unroll
  for (int r = 0; r < 4; ++r){
    bias0[r] = Wbp[nc * 128 + wid * 32 + 0  + q * 4 + r];
    bias1[r] = Wbp[nc * 128 + wid * 32 + 16 + q * 4 + r];
  }
  float cst[2];
  #pragma unroll
  for (int nt = 0; nt < 2; ++nt){
    int j = nc * 32 + wid * 8 + nt * 4 + q;
    cst[nt] = c0[(mc * 16 + s) * 1026 + 2 + j];
  }

  // coalesced stage mapping: row = 4*wid + lane>>4, col16 = lane&15
  const int row_l = (wid << 2) + (lane >> 4);
  const int col8  = (lane & 15) * 8;
  const int urow = tid >> 3, ucol = (tid & 7) * 8;   // for tid<128

  for (int it = 0; it <= SS; ++it){
    const int p = it & 1;
    // ---- stage h (coherent, coalesced 256B chunks) + u (cacheable) ----
    {
      const unsigned short* hs = hbuf + p * (BB * HDIM) + (mc * 16 + row_l) * HDIM + col8;
      h8 t0, t1, t2, t3, t4, t5, t6, t7;
      asm volatile("global_load_dwordx4 %0, %1, off sc0 sc1"              : "=&v"(t0) : "v"(hs) : "memory");
      asm volatile("global_load_dwordx4 %0, %1, off offset:256 sc0 sc1"   : "=&v"(t1) : "v"(hs) : "memory");
      asm volatile("global_load_dwordx4 %0, %1, off offset:512 sc0 sc1"   : "=&v"(t2) : "v"(hs) : "memory");
      asm volatile("global_load_dwordx4 %0, %1, off offset:768 sc0 sc1"   : "=&v"(t3) : "v"(hs) : "memory");
      asm volatile("global_load_dwordx4 %0, %1, off offset:1024 sc0 sc1"  : "=&v"(t4) : "v"(hs) : "memory");
      asm volatile("global_load_dwordx4 %0, %1, off offset:1280 sc0 sc1"  : "=&v"(t5) : "v"(hs) : "memory");
      asm volatile("global_load_dwordx4 %0, %1, off offset:1536 sc0 sc1"  : "=&v"(t6) : "v"(hs) : "memory");
      asm volatile("global_load_dwordx4 %0, %1, off offset:1792 sc0 sc1"  : "=&v"(t7) : "v"(hs) : "memory");
      h8 uvec = {};
      bool do_u = (it < SS) && (tid < 128);
      if (do_u)
        uvec = *(const h8*)&ubuf[(size_t)it * (BB * INPD) + (mc * 16 + urow) * INPD + ucol];
      asm volatile("s_waitcnt vmcnt(0)" ::: "memory");
      __builtin_amdgcn_sched_barrier(0);
      *(h8*)&acts[row_l][64 + col8 +    0] = t0;
      *(h8*)&acts[row_l][64 + col8 +  128] = t1;
      *(h8*)&acts[row_l][64 + col8 +  256] = t2;
      *(h8*)&acts[row_l][64 + col8 +  384] = t3;
      *(h8*)&acts[row_l][64 + col8 +  512] = t4;
      *(h8*)&acts[row_l][64 + col8 +  640] = t5;
      *(h8*)&acts[row_l][64 + col8 +  768] = t6;
      *(h8*)&acts[row_l][64 + col8 +  896] = t7;
      if (do_u) *(h8*)&acts[urow][ucol] = uvec;
    }
    __syncthreads();
    // ---- alpha partial MFMAs (independent of GEMM) ----
    if (it > 0){
      f32x4 pacc = {0.f, 0.f, 0.f, 0.f};
      #pragma unroll
      for (int i = 0; i < 8; ++i){
        int kt = 2 + wid * 8 + i;
        h8 b = *(const h8*)&acts[s][kt * 32 + q * 8];
        pacc = MFMA(W4[i], b, pacc);
      }
      if (q == 0){
        #pragma unroll
        for (int r = 0; r < 4; ++r) scratch[wid][s][r] = pacc[r];
      }
    }
    // ---- main GEMM (u+h cols; 4 independent acc chains) ----
    f32x4 a00, a01, a10, a11;
    if (it < SS){
      a00 = f32x4{bias0[0], bias0[1], bias0[2], bias0[3]};
      a10 = f32x4{bias1[0], bias1[1], bias1[2], bias1[3]};
      a01 = f32x4{0.f, 0.f, 0.f, 0.f};
      a11 = f32x4{0.f, 0.f, 0.f, 0.f};
      #pragma unroll
      for (int kt = 0; kt < KTM; kt += 2){
        h8 b0 = *(const h8*)&acts[s][kt * 32 + q * 8];
        h8 b1 = *(const h8*)&acts[s][(kt + 1) * 32 + q * 8];
        a00 = MFMA(W[0][kt],     b0, a00);
        a10 = MFMA(W[1][kt],     b0, a10);
        a01 = MFMA(W[0][kt + 1], b1, a01);
        a11 = MFMA(W[1][kt + 1], b1, a11);
      }
    }
    __syncthreads();
    // ---- 16-lane serial: alpha / x update (reads scratch, writes xst) ----
    if (it > 0 && tid < 16){
      float d0 = 0, d1 = 0, d2 = 0, d3 = 0;
      #pragma unroll
      for (int w = 0; w < 4; ++w){
        d0 += scratch[w][tid][0]; d1 += scratch[w][tid][1];
        d2 += scratch[w][tid][2]; d3 += scratch[w][tid][3];
      }
      int t = it - 1;
      int m = mc * 16 + tid;
      float a0 = sigm(d0 + wab0), a1 = sigm(d1 + wab1);
      float xt0 = d2 + wxb0, xt1 = d3 + wxb1;
      float x0 = xst[tid][0], x1 = xst[tid][1];
      float ta = tau_lds[tid][t];
      float xm0 = x0 + ta * (A00 * x0 + A01 * x1);
      float xm1 = x1 + ta * (A10 * x0 + A11 * x1);
      float xn0 = a0 * xm0 + (1.f - a0) * xt0;
      float xn1 = a1 * xm1 + (1.f - a1) * xt1;
      xst[tid][0] = xn0; xst[tid][1] = xn1;
      if (nc == 0){
        out[(size_t)m * 262656 + t * 1026 + 0] = xn0;
        out[(size_t)m * 262656 + t * 1026 + 1] = xn1;
        out[OUT3 + m * 512 + t * 2 + 0] = a0;
        out[OUT3 + m * 512 + t * 2 + 1] = a1;
        if (t == SS - 1){
          out[OUT1 + m * 1026 + 0] = xn0;
          out[OUT1 + m * 1026 + 1] = xn1;
          out[OUT2 + m * 1026 + 0] = c0[m * 1026 + 0];   // c_x never changes
          out[OUT2 + m * 1026 + 1] = c0[m * 1026 + 1];
        }
      }
    }
    __syncthreads();
    // ---- rank-2 x update + LSTM elementwise + publish + flag + poll ----
    if (it < SS){
      float x0 = xst[s][0], x1 = xst[s][1];
      f32x4 acc0 = a00 + a01;
      f32x4 acc1 = a10 + a11;
      #pragma unroll
      for (int r = 0; r < 4; ++r){
        acc0[r] += wxa_[0][r] * x0 + wxb_[0][r] * x1;
        acc1[r] += wxa_[1][r] * x0 + wxb_[1][r] * x1;
      }
      int m = mc * 16 + s;
      float hnv[2], cnv[2];
      #pragma unroll
      for (int nt = 0; nt < 2; ++nt){
        f32x4 a = nt ? acc1 : acc0;       // a[0]=i, a[1]=f, a[2]=g, a[3]=o
        float cn = sigm(a[1]) * cst[nt] + sigm(a[0]) * tanh_(a[2]);
        float hn = sigm(a[3]) * tanh_(cn);
        cst[nt] = cn; hnv[nt] = hn; cnv[nt] = cn;
      }
      // write-through publish (packed pair at permuted position q*2)
      {
        unsigned hv = (unsigned)f2h(hnv[0]) | ((unsigned)f2h(hnv[1]) << 16);
        unsigned short* hw = hbuf + (p ^ 1) * (BB * HDIM) + m * HDIM + nc * 32 + wid * 8 + q * 2;
        asm volatile("global_store_dword %0, %1, off sc0 sc1" :: "v"(hw), "v"(hv) : "memory");
      }
      asm volatile("s_waitcnt vmcnt(0)" ::: "memory");
      __syncthreads();
      if (tid == 0){
        unsigned* fl = bar + mc * 32 + nc;
        unsigned fv = (unsigned)(it + 1);
        asm volatile("global_store_dword %0, %1, off sc0 sc1" :: "v"(fl), "v"(fv) : "memory");
      }
      // out stores AFTER flag (off the ack chain; drained later)
      #pragma unroll
      for (int nt = 0; nt < 2; ++nt){
        int j = nc * 32 + wid * 8 + nt * 4 + q;
        out[(size_t)m * 262656 + it * 1026 + 2 + j] = hnv[nt];
        if (it == SS - 1){
          out[OUT1 + m * 1026 + 2 + j] = hnv[nt];
          out[OUT2 + m * 1026 + 2 + j] = cnv[nt];
        }
      }
      if (wid == 0){
        const unsigned* fp = bar + mc * 32 + (lane & 31);
        unsigned tgt = (unsigned)(it + 1);
        unsigned v;
        for (int spin = 0; spin < (1 << 20); ++spin){
          asm volatile("global_load_dword %0, %1, off sc0 sc1\n\ts_waitcnt vmcnt(0)"
                       : "=v"(v) : "v"(fp) : "memory");
          if (!__any((int)(v < tgt))) break;
        }
      }
      __syncthreads();
    }
  }
}

// ---------------- launch ----------------
extern "C" void kernel_launch(void* const* d_in, const int* in_sizes, int n_in,
                              void* d_out, int out_size, void* d_ws, size_t ws_size,
                              hipStream_t stream) {
  const float* rnn  = (const float*)d_in[0];
  const float* z0   = (const float*)d_in[1];
  const float* c0   = (const float*)d_in[2];
  const float* tau  = (const float*)d_in[3];
  const float* Amat = (const float*)d_in[4];
  const float* WU_w = (const float*)d_in[5];
  const float* WU_b = (const float*)d_in[6];
  const float* Wa_w = (const float*)d_in[7];
  const float* Wa_b = (const float*)d_in[8];
  const float* Wx_w = (const float*)d_in[9];
  const float* Wx_b = (const float*)d_in[10];

  char* ws = (char*)d_ws;
  unsigned short* Wp   = (unsigned short*)(ws + 0);          // 4096*1120*2 = 9,175,040
  float*          Wbp  = (float*)(ws + 9175040);             // 16,384
  unsigned short* W4p  = (unsigned short*)(ws + 9191424);    // 16*1120*2 = 35,840
  unsigned short* ubuf = (unsigned short*)(ws + 9227264);    // 256*128*64*2 = 4,194,304
  unsigned short* hbuf = (unsigned short*)(ws + 13421568);   // 2*128*1024*2 = 524,288
  unsigned*       bar  = (unsigned*)(ws + 13945856);         // 256 flags (8x32)

  prep_weights<<<4096, 256, 0, stream>>>(WU_w, WU_b, Wa_w, Wx_w, Wp, Wbp, W4p, bar);
  prep_ubuf<<<8192, 256, 0, stream>>>(rnn, ubuf);
  prep_h0<<<512, 256, 0, stream>>>(z0, hbuf);
  lstm_persist<<<256, 256, 0, stream>>>(Wp, Wbp, W4p, ubuf, hbuf, bar,
                                        z0, c0, tau, Amat, Wa_b, Wx_b, (float*)d_out);
}